// Round 2
// baseline (892.668 us; speedup 1.0000x reference)
//
#include <hip/hip_runtime.h>
#include <hip/hip_bf16.h>
#include <math.h>
#include <stdint.h>

// Problem constants
static constexpr int Bb = 8, S = 1024, E = 1152, H = 16, D = 72;
static constexpr int N3 = 3 * E;                 // 3456
static constexpr long QKV_T = (long)Bb * H * S * D;  // 9437184 elems per tensor

typedef __attribute__((ext_vector_type(8))) short bf16x8;
typedef __attribute__((ext_vector_type(4))) short bf16x4;
typedef __attribute__((ext_vector_type(4))) float f32x4;

#define MFMA16(A, B, C) __builtin_amdgcn_mfma_f32_16x16x32_bf16(A, B, C, 0, 0, 0)

__device__ __forceinline__ short f2bf(float f) {
    __hip_bfloat16 h = __float2bfloat16(f);
    return __builtin_bit_cast(short, h);
}
__device__ __forceinline__ float bf2f(short s) {
    unsigned u = ((unsigned)(unsigned short)s) << 16;
    return __builtin_bit_cast(float, u);
}

// ---------------------------------------------------------------------------
// Kernel 1: fused QKV projection.  C[8192, 3456] = X @ W + b, where X depends
// on the output column group (q/k/v).  Split-bf16 (hi/lo) 3-term MFMA for
// near-fp32 accuracy.  Output scattered to Q/K/V bf16 [B,H,S,D] in workspace.
// ---------------------------------------------------------------------------
__global__ __launch_bounds__(256)
void qkv_proj(const float* __restrict__ Aq, const float* __restrict__ Ak,
              const float* __restrict__ Av, const float* __restrict__ W,
              const float* __restrict__ bias, short* __restrict__ qkv)
{
    constexpr int BM = 128, BN = 128, BK = 32, LDK = 40;  // +8 pad: 2-way banks
    __shared__ short aHi[BM][LDK], aLo[BM][LDK], bHi[BN][LDK], bLo[BN][LDK];

    const int tid = threadIdx.x;
    const int m0 = blockIdx.y * BM;
    const int n0 = blockIdx.x * BN;
    const int which = n0 / E;  // 0=q 1=k 2=v (1152/128=9 blocks per group)
    const float* A = (which == 0) ? Aq : ((which == 1) ? Ak : Av);

    const int lane = tid & 63, wid = tid >> 6;
    const int c = lane & 15, g = lane >> 4;
    const int wm = (wid >> 1) * 64, wn = (wid & 1) * 64;

    f32x4 acc[4][4] = {};

    for (int k0 = 0; k0 < E; k0 += BK) {
        __syncthreads();
        // Stage A tile [128][32] fp32 -> hi/lo bf16 (1024 float4 chunks)
        for (int ii = 0; ii < 4; ++ii) {
            int ch = tid + ii * 256;
            int row = ch >> 3, col = (ch & 7) * 4;
            float4 v = *reinterpret_cast<const float4*>(A + (long)(m0 + row) * E + k0 + col);
            short h0 = f2bf(v.x), h1 = f2bf(v.y), h2 = f2bf(v.z), h3 = f2bf(v.w);
            bf16x4 hi = {h0, h1, h2, h3};
            bf16x4 lo = {f2bf(v.x - bf2f(h0)), f2bf(v.y - bf2f(h1)),
                         f2bf(v.z - bf2f(h2)), f2bf(v.w - bf2f(h3))};
            *reinterpret_cast<bf16x4*>(&aHi[row][col]) = hi;
            *reinterpret_cast<bf16x4*>(&aLo[row][col]) = lo;
        }
        // Stage B tile [32][128] fp32 -> transposed hi/lo bf16 [n][k]
        for (int ii = 0; ii < 4; ++ii) {
            int ch = tid + ii * 256;
            int kk = ch >> 5, nn = (ch & 31) * 4;
            float4 v = *reinterpret_cast<const float4*>(W + (long)(k0 + kk) * N3 + n0 + nn);
            float vv[4] = {v.x, v.y, v.z, v.w};
            for (int x = 0; x < 4; ++x) {
                short hb = f2bf(vv[x]);
                bHi[nn + x][kk] = hb;
                bLo[nn + x][kk] = f2bf(vv[x] - bf2f(hb));
            }
        }
        __syncthreads();

        bf16x8 ah[4], al[4], bh[4], bl[4];
        for (int i = 0; i < 4; ++i) {
            ah[i] = *reinterpret_cast<const bf16x8*>(&aHi[wm + i * 16 + c][g * 8]);
            al[i] = *reinterpret_cast<const bf16x8*>(&aLo[wm + i * 16 + c][g * 8]);
            bh[i] = *reinterpret_cast<const bf16x8*>(&bHi[wn + i * 16 + c][g * 8]);
            bl[i] = *reinterpret_cast<const bf16x8*>(&bLo[wn + i * 16 + c][g * 8]);
        }
        for (int i = 0; i < 4; ++i)
            for (int j = 0; j < 4; ++j) {
                acc[i][j] = MFMA16(ah[i], bh[j], acc[i][j]);
                acc[i][j] = MFMA16(ah[i], bl[j], acc[i][j]);
                acc[i][j] = MFMA16(al[i], bh[j], acc[i][j]);
            }
    }

    // Epilogue: scatter into [which][B,H,S,D] bf16
    for (int j = 0; j < 4; ++j) {
        int n = n0 + wn + j * 16 + c;
        float bv = bias[n];
        int nl = n - which * E;
        int hh = nl / D, dd = nl % D;
        for (int i = 0; i < 4; ++i) {
            int rowb = m0 + wm + i * 16 + g * 4;
            for (int r = 0; r < 4; ++r) {
                int row = rowb + r;
                int b = row >> 10, s = row & 1023;
                long idx = (long)which * QKV_T + (((long)(b * H + hh)) * S + s) * D + dd;
                qkv[idx] = f2bf(acc[i][j][r] + bv);
            }
        }
    }
}

// ---------------------------------------------------------------------------
// Kernel 2: flash attention.  One block = 128 q-rows of one (b,h); 4 waves,
// each owns 32 rows.  KV tiles of 64.  Online softmax in acc layout
// (row = g*4+r, col = c), row reduce via 16-lane shfl_xor.
// ---------------------------------------------------------------------------
__global__ __launch_bounds__(256)
void attn_fwd(const short* __restrict__ qkv, short* __restrict__ attn)
{
    __shared__ short k_lds[64][96];      // [k'][d], d 72..95 zeroed
    __shared__ short v_t[80][72];        // [d][k'], rows 72..79 zeroed, +8 col pad
    __shared__ short p_lds[4][32][72];   // per-wave P, +8 col pad

    const int tid = threadIdx.x, lane = tid & 63, wid = tid >> 6;
    const int c = lane & 15, g = lane >> 4;
    const int q0 = blockIdx.x * 128;
    const int bh = blockIdx.y;
    const int b = bh >> 4, h = bh & 15;

    const short* Qb = qkv + (long)bh * (S * D);
    const short* Kb = qkv + QKV_T + (long)bh * (S * D);
    const short* Vb = qkv + 2 * QKV_T + (long)bh * (S * D);

    // zero pads (stay zero across tiles)
    for (int i = tid; i < 64 * 24; i += 256) k_lds[i / 24][72 + i % 24] = 0;
    for (int i = tid; i < 8 * 72; i += 256) v_t[72 + i / 72][i % 72] = 0;

    // Q fragments hoisted (registers); D=72 tail: only g==0 holds d=64..71
    bf16x8 qf[2][3];
    const bf16x8 zf = {};
    for (int i = 0; i < 2; ++i) {
        const short* qr = Qb + (long)(q0 + wid * 32 + i * 16 + c) * D;
        qf[i][0] = *reinterpret_cast<const bf16x8*>(qr + g * 8);
        qf[i][1] = *reinterpret_cast<const bf16x8*>(qr + 32 + g * 8);
        qf[i][2] = (g == 0) ? *reinterpret_cast<const bf16x8*>(qr + 64) : zf;
    }

    const float scale = 0.11785113019775793f;  // 72^-0.5
    float m_run[2][4], l_run[2][4];
    f32x4 accO[2][5] = {};
    for (int i = 0; i < 2; ++i)
        for (int r = 0; r < 4; ++r) { m_run[i][r] = -__builtin_inff(); l_run[i][r] = 0.f; }

    for (int kt = 0; kt < 16; ++kt) {
        __syncthreads();
        // Stage K [64][72] linear; V transposed into v_t[d][k']
        const short* Ks = Kb + kt * 64 * D;
        const short* Vs = Vb + kt * 64 * D;
        for (int ii = 0; ii < 5; ++ii) {
            int ch = tid + ii * 256;  // 64*18 = 1152 chunks of 4 bf16
            if (ch < 1152) {
                int kp = ch / 18, dq = ch % 18;
                uint64_t kvv = *reinterpret_cast<const uint64_t*>(Ks + kp * D + dq * 4);
                *reinterpret_cast<uint64_t*>(&k_lds[kp][dq * 4]) = kvv;
                uint64_t vvv = *reinterpret_cast<const uint64_t*>(Vs + kp * D + dq * 4);
                short* sp = reinterpret_cast<short*>(&vvv);
                v_t[dq * 4 + 0][kp] = sp[0];
                v_t[dq * 4 + 1][kp] = sp[1];
                v_t[dq * 4 + 2][kp] = sp[2];
                v_t[dq * 4 + 3][kp] = sp[3];
            }
        }
        __syncthreads();

        // S = Q K^T  (K padded to 96 via zeroed A-frag tail + zeroed LDS cols)
        f32x4 sAcc[2][4] = {};
        for (int dc = 0; dc < 3; ++dc) {
            bf16x8 bfr[4];
            for (int j = 0; j < 4; ++j)
                bfr[j] = *reinterpret_cast<const bf16x8*>(&k_lds[j * 16 + c][dc * 32 + g * 8]);
            for (int i = 0; i < 2; ++i)
                for (int j = 0; j < 4; ++j)
                    sAcc[i][j] = MFMA16(qf[i][dc], bfr[j], sAcc[i][j]);
        }

        // online softmax
        for (int i = 0; i < 2; ++i) {
            for (int r = 0; r < 4; ++r) {
                float sv[4];
                float mx = -__builtin_inff();
                for (int j = 0; j < 4; ++j) { sv[j] = sAcc[i][j][r] * scale; mx = fmaxf(mx, sv[j]); }
                mx = fmaxf(mx, __shfl_xor(mx, 1));
                mx = fmaxf(mx, __shfl_xor(mx, 2));
                mx = fmaxf(mx, __shfl_xor(mx, 4));
                mx = fmaxf(mx, __shfl_xor(mx, 8));
                float m_new = fmaxf(m_run[i][r], mx);
                float corr = __expf(m_run[i][r] - m_new);
                m_run[i][r] = m_new;
                float ps = 0.f;
                int prow = i * 16 + g * 4 + r;
                for (int j = 0; j < 4; ++j) {
                    float p = __expf(sv[j] - m_new);
                    ps += p;
                    p_lds[wid][prow][j * 16 + c] = f2bf(p);
                }
                ps += __shfl_xor(ps, 1);
                ps += __shfl_xor(ps, 2);
                ps += __shfl_xor(ps, 4);
                ps += __shfl_xor(ps, 8);
                l_run[i][r] = l_run[i][r] * corr + ps;
                for (int n = 0; n < 5; ++n) accO[i][n][r] *= corr;
            }
        }

        // O += P V   (same-wave LDS round-trip for P; compiler orders lgkmcnt)
        for (int ks = 0; ks < 2; ++ks) {
            bf16x8 pa[2];
            for (int i = 0; i < 2; ++i)
                pa[i] = *reinterpret_cast<const bf16x8*>(&p_lds[wid][i * 16 + c][ks * 32 + g * 8]);
            for (int n = 0; n < 5; ++n) {
                bf16x8 vb = *reinterpret_cast<const bf16x8*>(&v_t[n * 16 + c][ks * 32 + g * 8]);
                for (int i = 0; i < 2; ++i)
                    accO[i][n] = MFMA16(pa[i], vb, accO[i][n]);
            }
        }
    }

    // write attn [B*S][E] bf16, e = h*72 + d, mask d<72
    for (int i = 0; i < 2; ++i) {
        for (int n = 0; n < 5; ++n) {
            int dd = n * 16 + c;
            if (dd >= D) continue;
            for (int r = 0; r < 4; ++r) {
                int row = q0 + wid * 32 + i * 16 + g * 4 + r;
                float val = accO[i][n][r] / l_run[i][r];
                attn[((long)(b * S + row)) * E + h * D + dd] = f2bf(val);
            }
        }
    }
}

// ---------------------------------------------------------------------------
// Kernel 3: out projection.  out[8192,1152] = attn(bf16) @ out_w(f32->bf16) + b
// Single bf16 MFMA; output written as FP32 (reference output dtype is float32).
// ---------------------------------------------------------------------------
__global__ __launch_bounds__(256)
void out_proj(const short* __restrict__ Aat, const float* __restrict__ W,
              const float* __restrict__ bias, float* __restrict__ out)
{
    constexpr int BM = 128, BN = 128, BK = 32, LDK = 40;
    __shared__ short aT[BM][LDK], bT[BN][LDK];
    const int tid = threadIdx.x;
    const int m0 = blockIdx.y * BM, n0 = blockIdx.x * BN;
    const int lane = tid & 63, wid = tid >> 6;
    const int c = lane & 15, g = lane >> 4;
    const int wm = (wid >> 1) * 64, wn = (wid & 1) * 64;

    f32x4 acc[4][4] = {};
    for (int k0 = 0; k0 < E; k0 += BK) {
        __syncthreads();
        // stage A bf16 [128][32] (512 chunks of 8 shorts)
        for (int ii = 0; ii < 2; ++ii) {
            int ch = tid + ii * 256;
            int row = ch >> 2, cc = (ch & 3) * 8;
            *reinterpret_cast<bf16x8*>(&aT[row][cc]) =
                *reinterpret_cast<const bf16x8*>(Aat + (long)(m0 + row) * E + k0 + cc);
        }
        // stage B [32][128] fp32 -> transposed bf16 [n][k]
        for (int ii = 0; ii < 4; ++ii) {
            int ch = tid + ii * 256;
            int kk = ch >> 5, nn = (ch & 31) * 4;
            float4 v = *reinterpret_cast<const float4*>(W + (long)(k0 + kk) * E + n0 + nn);
            bT[nn + 0][kk] = f2bf(v.x);
            bT[nn + 1][kk] = f2bf(v.y);
            bT[nn + 2][kk] = f2bf(v.z);
            bT[nn + 3][kk] = f2bf(v.w);
        }
        __syncthreads();

        bf16x8 af[4], bf[4];
        for (int i = 0; i < 4; ++i) {
            af[i] = *reinterpret_cast<const bf16x8*>(&aT[wm + i * 16 + c][g * 8]);
            bf[i] = *reinterpret_cast<const bf16x8*>(&bT[wn + i * 16 + c][g * 8]);
        }
        for (int i = 0; i < 4; ++i)
            for (int j = 0; j < 4; ++j)
                acc[i][j] = MFMA16(af[i], bf[j], acc[i][j]);
    }

    for (int j = 0; j < 4; ++j) {
        int n = n0 + wn + j * 16 + c;
        float bv = bias[n];
        for (int i = 0; i < 4; ++i)
            for (int r = 0; r < 4; ++r) {
                int row = m0 + wm + i * 16 + g * 4 + r;
                out[(long)row * E + n] = acc[i][j][r] + bv;
            }
    }
}

// ---------------------------------------------------------------------------
extern "C" void kernel_launch(void* const* d_in, const int* in_sizes, int n_in,
                              void* d_out, int out_size, void* d_ws, size_t ws_size,
                              hipStream_t stream)
{
    const float* q     = (const float*)d_in[0];
    const float* k     = (const float*)d_in[1];
    const float* v     = (const float*)d_in[2];
    const float* w_in  = (const float*)d_in[3];
    const float* b_in  = (const float*)d_in[4];
    const float* w_out = (const float*)d_in[5];
    const float* b_out = (const float*)d_in[6];

    short* ws   = (short*)d_ws;
    short* qkv  = ws;                  // 3 * 9437184 bf16 (Q,K,V in [B,H,S,D])
    short* attn = ws + 3 * QKV_T;      // 9437184 bf16 ([B*S][E])
    float* out  = (float*)d_out;       // fp32 output (reference dtype)

    qkv_proj<<<dim3(27, 64), 256, 0, stream>>>(q, k, v, w_in, b_in, qkv);
    attn_fwd<<<dim3(8, 128), 256, 0, stream>>>(qkv, attn);
    out_proj<<<dim3(9, 64), 256, 0, stream>>>(attn, w_out, b_out, out);
}

// Round 3
// 515.389 us; speedup vs baseline: 1.7320x; 1.7320x over previous
//
#include <hip/hip_runtime.h>
#include <hip/hip_bf16.h>
#include <math.h>
#include <stdint.h>

// Problem constants
static constexpr int Bb = 8, S = 1024, E = 1152, H = 16, D = 72;
static constexpr int N3 = 3 * E;                 // 3456
static constexpr long QKV_T = (long)Bb * H * S * D;  // 9437184 elems per tensor

typedef __attribute__((ext_vector_type(8))) short bf16x8;
typedef __attribute__((ext_vector_type(4))) short bf16x4;
typedef __attribute__((ext_vector_type(4))) float f32x4;

#define MFMA16(A, B, C) __builtin_amdgcn_mfma_f32_16x16x32_bf16(A, B, C, 0, 0, 0)

__device__ __forceinline__ short f2bf(float f) {
    __hip_bfloat16 h = __float2bfloat16(f);
    return __builtin_bit_cast(short, h);
}
__device__ __forceinline__ float bf2f(short s) {
    unsigned u = ((unsigned)(unsigned short)s) << 16;
    return __builtin_bit_cast(float, u);
}

__device__ __forceinline__ void gload_lds16(const void* g, void* l) {
    __builtin_amdgcn_global_load_lds(
        (const __attribute__((address_space(1))) unsigned int*)g,
        (__attribute__((address_space(3))) unsigned int*)l, 16, 0, 0);
}

// ---------------------------------------------------------------------------
// Kernel 0: one-time W transpose+convert.  W[1152][3456] f32 -> WT[3456][1152] bf16
// ---------------------------------------------------------------------------
__global__ __launch_bounds__(256)
void wt_conv(const float* __restrict__ W, short* __restrict__ WT)
{
    __shared__ float tt[32][33];
    const int n0 = blockIdx.x * 32;   // output row group (W column)
    const int k0 = blockIdx.y * 32;   // output col group (W row)
    const int t = threadIdx.x;
    {
        int r = t >> 3, c4 = (t & 7) * 4;
        float4 v = *reinterpret_cast<const float4*>(W + (long)(k0 + r) * N3 + n0 + c4);
        tt[r][c4 + 0] = v.x; tt[r][c4 + 1] = v.y; tt[r][c4 + 2] = v.z; tt[r][c4 + 3] = v.w;
    }
    __syncthreads();
    {
        int n = t >> 3, k4 = (t & 7) * 4;
        bf16x4 o = {f2bf(tt[k4 + 0][n]), f2bf(tt[k4 + 1][n]),
                    f2bf(tt[k4 + 2][n]), f2bf(tt[k4 + 3][n])};
        *reinterpret_cast<bf16x4*>(WT + (long)(n0 + n) * E + k0 + k4) = o;
    }
}

// ---------------------------------------------------------------------------
// Kernel 1: fused QKV projection.  C[8192, 3456] = X @ W + b, X selected per
// column group (q/k/v).  2-term split-bf16 MFMA (A hi/lo, B hi): residual
// error ~1e-3 at q-level, below bf16-storage rounding.  B staged via
// global_load_lds from pre-transposed bf16 WT (linear, conflict-free).
// ---------------------------------------------------------------------------
__global__ __launch_bounds__(256)
void qkv_proj(const float* __restrict__ Aq, const float* __restrict__ Ak,
              const float* __restrict__ Av, const short* __restrict__ WT,
              const float* __restrict__ bias, short* __restrict__ qkv)
{
    constexpr int BM = 128, BN = 128, BK = 32, LDK = 40;  // A pad: 2-way banks
    __shared__ short aHi[BM][LDK], aLo[BM][LDK];
    __shared__ short bW[BN][BK];      // linear: global_load_lds dest

    const int tid = threadIdx.x;
    const int m0 = blockIdx.y * BM;
    const int n0 = blockIdx.x * BN;
    const int which = n0 / E;  // 0=q 1=k 2=v
    const float* A = (which == 0) ? Aq : ((which == 1) ? Ak : Av);

    const int lane = tid & 63, wid = tid >> 6;
    const int c = lane & 15, g = lane >> 4;
    const int wm = (wid >> 1) * 64, wn = (wid & 1) * 64;

    f32x4 acc[4][4] = {};

    for (int k0 = 0; k0 < E; k0 += BK) {
        __syncthreads();
        // Stage B tile [128 n][32 k] bf16 via global_load_lds (2 insts/wave)
        for (int t = 0; t < 2; ++t) {
            int row = wid * 32 + t * 16;
            const short* src = WT + (long)(n0 + row + (lane >> 2)) * E + k0 + (lane & 3) * 8;
            gload_lds16(src, &bW[row][0]);
        }
        // Stage A tile [128][32] fp32 -> hi/lo bf16
        for (int ii = 0; ii < 4; ++ii) {
            int ch = tid + ii * 256;
            int row = ch >> 3, col = (ch & 7) * 4;
            float4 v = *reinterpret_cast<const float4*>(A + (long)(m0 + row) * E + k0 + col);
            short h0 = f2bf(v.x), h1 = f2bf(v.y), h2 = f2bf(v.z), h3 = f2bf(v.w);
            bf16x4 hi = {h0, h1, h2, h3};
            bf16x4 lo = {f2bf(v.x - bf2f(h0)), f2bf(v.y - bf2f(h1)),
                         f2bf(v.z - bf2f(h2)), f2bf(v.w - bf2f(h3))};
            *reinterpret_cast<bf16x4*>(&aHi[row][col]) = hi;
            *reinterpret_cast<bf16x4*>(&aLo[row][col]) = lo;
        }
        __syncthreads();

        bf16x8 ah[4], al[4], bh[4];
        for (int i = 0; i < 4; ++i) {
            ah[i] = *reinterpret_cast<const bf16x8*>(&aHi[wm + i * 16 + c][g * 8]);
            al[i] = *reinterpret_cast<const bf16x8*>(&aLo[wm + i * 16 + c][g * 8]);
            bh[i] = *reinterpret_cast<const bf16x8*>(&bW[wn + i * 16 + c][g * 8]);
        }
        for (int i = 0; i < 4; ++i)
            for (int j = 0; j < 4; ++j) {
                acc[i][j] = MFMA16(ah[i], bh[j], acc[i][j]);
                acc[i][j] = MFMA16(al[i], bh[j], acc[i][j]);
            }
    }

    // Epilogue: scatter into [which][B,H,S,D] bf16
    for (int j = 0; j < 4; ++j) {
        int n = n0 + wn + j * 16 + c;
        float bv = bias[n];
        int nl = n - which * E;
        int hh = nl / D, dd = nl % D;
        for (int i = 0; i < 4; ++i) {
            int rowb = m0 + wm + i * 16 + g * 4;
            for (int r = 0; r < 4; ++r) {
                int row = rowb + r;
                int b = row >> 10, s = row & 1023;
                long idx = (long)which * QKV_T + (((long)(b * H + hh)) * S + s) * D + dd;
                qkv[idx] = f2bf(acc[i][j][r] + bv);
            }
        }
    }
}

// ---------------------------------------------------------------------------
// Kernel 2: flash attention.  One block = 128 q-rows of one (b,h); 4 waves,
// each owns 32 rows.  KV tiles of 64.  Online softmax in acc layout
// (row = g*4+r, col = c), row reduce via 16-lane shfl_xor.
// ---------------------------------------------------------------------------
__global__ __launch_bounds__(256)
void attn_fwd(const short* __restrict__ qkv, short* __restrict__ attn)
{
    __shared__ short k_lds[64][96];      // [k'][d], d 72..95 zeroed
    __shared__ short v_t[80][72];        // [d][k'], rows 72..79 zeroed
    __shared__ short p_lds[4][32][72];   // per-wave P

    const int tid = threadIdx.x, lane = tid & 63, wid = tid >> 6;
    const int c = lane & 15, g = lane >> 4;
    const int q0 = blockIdx.x * 128;
    const int bh = blockIdx.y;
    const int b = bh >> 4, h = bh & 15;

    const short* Qb = qkv + (long)bh * (S * D);
    const short* Kb = qkv + QKV_T + (long)bh * (S * D);
    const short* Vb = qkv + 2 * QKV_T + (long)bh * (S * D);

    for (int i = tid; i < 64 * 24; i += 256) k_lds[i / 24][72 + i % 24] = 0;
    for (int i = tid; i < 8 * 72; i += 256) v_t[72 + i / 72][i % 72] = 0;

    bf16x8 qf[2][3];
    const bf16x8 zf = {};
    for (int i = 0; i < 2; ++i) {
        const short* qr = Qb + (long)(q0 + wid * 32 + i * 16 + c) * D;
        qf[i][0] = *reinterpret_cast<const bf16x8*>(qr + g * 8);
        qf[i][1] = *reinterpret_cast<const bf16x8*>(qr + 32 + g * 8);
        qf[i][2] = (g == 0) ? *reinterpret_cast<const bf16x8*>(qr + 64) : zf;
    }

    const float scale = 0.11785113019775793f;  // 72^-0.5
    float m_run[2][4], l_run[2][4];
    f32x4 accO[2][5] = {};
    for (int i = 0; i < 2; ++i)
        for (int r = 0; r < 4; ++r) { m_run[i][r] = -__builtin_inff(); l_run[i][r] = 0.f; }

    for (int kt = 0; kt < 16; ++kt) {
        __syncthreads();
        const short* Ks = Kb + kt * 64 * D;
        const short* Vs = Vb + kt * 64 * D;
        for (int ii = 0; ii < 5; ++ii) {
            int ch = tid + ii * 256;
            if (ch < 1152) {
                int kp = ch / 18, dq = ch % 18;
                uint64_t kvv = *reinterpret_cast<const uint64_t*>(Ks + kp * D + dq * 4);
                *reinterpret_cast<uint64_t*>(&k_lds[kp][dq * 4]) = kvv;
                uint64_t vvv = *reinterpret_cast<const uint64_t*>(Vs + kp * D + dq * 4);
                short* sp = reinterpret_cast<short*>(&vvv);
                v_t[dq * 4 + 0][kp] = sp[0];
                v_t[dq * 4 + 1][kp] = sp[1];
                v_t[dq * 4 + 2][kp] = sp[2];
                v_t[dq * 4 + 3][kp] = sp[3];
            }
        }
        __syncthreads();

        f32x4 sAcc[2][4] = {};
        for (int dc = 0; dc < 3; ++dc) {
            bf16x8 bfr[4];
            for (int j = 0; j < 4; ++j)
                bfr[j] = *reinterpret_cast<const bf16x8*>(&k_lds[j * 16 + c][dc * 32 + g * 8]);
            for (int i = 0; i < 2; ++i)
                for (int j = 0; j < 4; ++j)
                    sAcc[i][j] = MFMA16(qf[i][dc], bfr[j], sAcc[i][j]);
        }

        for (int i = 0; i < 2; ++i) {
            for (int r = 0; r < 4; ++r) {
                float sv[4];
                float mx = -__builtin_inff();
                for (int j = 0; j < 4; ++j) { sv[j] = sAcc[i][j][r] * scale; mx = fmaxf(mx, sv[j]); }
                mx = fmaxf(mx, __shfl_xor(mx, 1));
                mx = fmaxf(mx, __shfl_xor(mx, 2));
                mx = fmaxf(mx, __shfl_xor(mx, 4));
                mx = fmaxf(mx, __shfl_xor(mx, 8));
                float m_new = fmaxf(m_run[i][r], mx);
                float corr = __expf(m_run[i][r] - m_new);
                m_run[i][r] = m_new;
                float ps = 0.f;
                int prow = i * 16 + g * 4 + r;
                for (int j = 0; j < 4; ++j) {
                    float p = __expf(sv[j] - m_new);
                    ps += p;
                    p_lds[wid][prow][j * 16 + c] = f2bf(p);
                }
                ps += __shfl_xor(ps, 1);
                ps += __shfl_xor(ps, 2);
                ps += __shfl_xor(ps, 4);
                ps += __shfl_xor(ps, 8);
                l_run[i][r] = l_run[i][r] * corr + ps;
                for (int n = 0; n < 5; ++n) accO[i][n][r] *= corr;
            }
        }

        for (int ks = 0; ks < 2; ++ks) {
            bf16x8 pa[2];
            for (int i = 0; i < 2; ++i)
                pa[i] = *reinterpret_cast<const bf16x8*>(&p_lds[wid][i * 16 + c][ks * 32 + g * 8]);
            for (int n = 0; n < 5; ++n) {
                bf16x8 vb = *reinterpret_cast<const bf16x8*>(&v_t[n * 16 + c][ks * 32 + g * 8]);
                for (int i = 0; i < 2; ++i)
                    accO[i][n] = MFMA16(pa[i], vb, accO[i][n]);
            }
        }
    }

    for (int i = 0; i < 2; ++i) {
        for (int n = 0; n < 5; ++n) {
            int dd = n * 16 + c;
            if (dd >= D) continue;
            for (int r = 0; r < 4; ++r) {
                int row = q0 + wid * 32 + i * 16 + g * 4 + r;
                float val = accO[i][n][r] / l_run[i][r];
                attn[((long)(b * S + row)) * E + h * D + dd] = f2bf(val);
            }
        }
    }
}

// ---------------------------------------------------------------------------
// Kernel 3: out projection.  out[8192,1152] = attn(bf16) @ out_w(f32->bf16) + b
// FP32 output (reference output dtype).
// ---------------------------------------------------------------------------
__global__ __launch_bounds__(256)
void out_proj(const short* __restrict__ Aat, const float* __restrict__ W,
              const float* __restrict__ bias, float* __restrict__ out)
{
    constexpr int BM = 128, BN = 128, BK = 32, LDK = 40;
    __shared__ short aT[BM][LDK], bT[BN][LDK];
    const int tid = threadIdx.x;
    const int m0 = blockIdx.y * BM, n0 = blockIdx.x * BN;
    const int lane = tid & 63, wid = tid >> 6;
    const int c = lane & 15, g = lane >> 4;
    const int wm = (wid >> 1) * 64, wn = (wid & 1) * 64;

    f32x4 acc[4][4] = {};
    for (int k0 = 0; k0 < E; k0 += BK) {
        __syncthreads();
        for (int ii = 0; ii < 2; ++ii) {
            int ch = tid + ii * 256;
            int row = ch >> 2, cc = (ch & 3) * 8;
            *reinterpret_cast<bf16x8*>(&aT[row][cc]) =
                *reinterpret_cast<const bf16x8*>(Aat + (long)(m0 + row) * E + k0 + cc);
        }
        for (int ii = 0; ii < 4; ++ii) {
            int ch = tid + ii * 256;
            int kk = ch >> 5, nn = (ch & 31) * 4;
            float4 v = *reinterpret_cast<const float4*>(W + (long)(k0 + kk) * E + n0 + nn);
            bT[nn + 0][kk] = f2bf(v.x);
            bT[nn + 1][kk] = f2bf(v.y);
            bT[nn + 2][kk] = f2bf(v.z);
            bT[nn + 3][kk] = f2bf(v.w);
        }
        __syncthreads();

        bf16x8 af[4], bf[4];
        for (int i = 0; i < 4; ++i) {
            af[i] = *reinterpret_cast<const bf16x8*>(&aT[wm + i * 16 + c][g * 8]);
            bf[i] = *reinterpret_cast<const bf16x8*>(&bT[wn + i * 16 + c][g * 8]);
        }
        for (int i = 0; i < 4; ++i)
            for (int j = 0; j < 4; ++j)
                acc[i][j] = MFMA16(af[i], bf[j], acc[i][j]);
    }

    for (int j = 0; j < 4; ++j) {
        int n = n0 + wn + j * 16 + c;
        float bv = bias[n];
        for (int i = 0; i < 4; ++i)
            for (int r = 0; r < 4; ++r) {
                int row = m0 + wm + i * 16 + g * 4 + r;
                out[(long)row * E + n] = acc[i][j][r] + bv;
            }
    }
}

// ---------------------------------------------------------------------------
extern "C" void kernel_launch(void* const* d_in, const int* in_sizes, int n_in,
                              void* d_out, int out_size, void* d_ws, size_t ws_size,
                              hipStream_t stream)
{
    const float* q     = (const float*)d_in[0];
    const float* k     = (const float*)d_in[1];
    const float* v     = (const float*)d_in[2];
    const float* w_in  = (const float*)d_in[3];
    const float* b_in  = (const float*)d_in[4];
    const float* w_out = (const float*)d_in[5];
    const float* b_out = (const float*)d_in[6];

    short* ws   = (short*)d_ws;
    short* qkv  = ws;                  // 3 * 9437184 bf16 (Q,K,V in [B,H,S,D])
    short* attn = ws + 3 * QKV_T;      // 9437184 bf16 ([B*S][E])
    short* WT   = ws + 4 * QKV_T;      // 3456*1152 bf16 (W transposed)
    float* out  = (float*)d_out;       // fp32 output

    wt_conv<<<dim3(108, 36), 256, 0, stream>>>(w_in, WT);
    qkv_proj<<<dim3(27, 64), 256, 0, stream>>>(q, k, v, WT, b_in, qkv);
    attn_fwd<<<dim3(8, 128), 256, 0, stream>>>(qkv, attn);
    out_proj<<<dim3(9, 64), 256, 0, stream>>>(attn, w_out, b_out, out);
}

// Round 5
// 484.372 us; speedup vs baseline: 1.8429x; 1.0640x over previous
//
#include <hip/hip_runtime.h>
#include <hip/hip_bf16.h>
#include <math.h>
#include <stdint.h>

// Problem constants
static constexpr int Bb = 8, S = 1024, E = 1152, H = 16, D = 72;
static constexpr int N3 = 3 * E;                 // 3456
static constexpr long QKV_T = (long)Bb * H * S * D;  // 9437184 elems per tensor

typedef __attribute__((ext_vector_type(8))) short bf16x8;
typedef __attribute__((ext_vector_type(4))) short bf16x4;
typedef __attribute__((ext_vector_type(4))) float f32x4;

#define MFMA16(A, B, C) __builtin_amdgcn_mfma_f32_16x16x32_bf16(A, B, C, 0, 0, 0)

__device__ __forceinline__ short f2bf(float f) {
    __hip_bfloat16 h = __float2bfloat16(f);
    return __builtin_bit_cast(short, h);
}
__device__ __forceinline__ float bf2f(short s) {
    unsigned u = ((unsigned)(unsigned short)s) << 16;
    return __builtin_bit_cast(float, u);
}

__device__ __forceinline__ void gload_lds16(const void* g, void* l) {
    __builtin_amdgcn_global_load_lds(
        (const __attribute__((address_space(1))) unsigned int*)g,
        (__attribute__((address_space(3))) unsigned int*)l, 16, 0, 0);
}

// ---------------------------------------------------------------------------
// Kernel A: transpose+convert.  W[K][N] f32 -> WT[N][K] bf16.
// ---------------------------------------------------------------------------
__global__ __launch_bounds__(256)
void wt_conv(const float* __restrict__ W, short* __restrict__ WT, int K, int N)
{
    __shared__ float tt[32][33];
    const int n0 = blockIdx.x * 32, k0 = blockIdx.y * 32;
    const int t = threadIdx.x;
    {
        int r = t >> 3, c4 = (t & 7) * 4;
        float4 v = *reinterpret_cast<const float4*>(W + (long)(k0 + r) * N + n0 + c4);
        tt[r][c4 + 0] = v.x; tt[r][c4 + 1] = v.y; tt[r][c4 + 2] = v.z; tt[r][c4 + 3] = v.w;
    }
    __syncthreads();
    {
        int n = t >> 3, k4 = (t & 7) * 4;
        bf16x4 o = {f2bf(tt[k4 + 0][n]), f2bf(tt[k4 + 1][n]),
                    f2bf(tt[k4 + 2][n]), f2bf(tt[k4 + 3][n])};
        *reinterpret_cast<bf16x4*>(WT + (long)(n0 + n) * K + k0 + k4) = o;
    }
}

// ---------------------------------------------------------------------------
// Kernel B: split f32 -> hi/lo bf16.  n4 = element_count / 4.
// ---------------------------------------------------------------------------
__global__ __launch_bounds__(256)
void presplit(const float* __restrict__ X, short* __restrict__ XH,
              short* __restrict__ XL, long n4)
{
    for (long i = (long)blockIdx.x * 256 + threadIdx.x; i < n4; i += (long)gridDim.x * 256) {
        float4 v = reinterpret_cast<const float4*>(X)[i];
        short h0 = f2bf(v.x), h1 = f2bf(v.y), h2 = f2bf(v.z), h3 = f2bf(v.w);
        bf16x4 hi = {h0, h1, h2, h3};
        bf16x4 lo = {f2bf(v.x - bf2f(h0)), f2bf(v.y - bf2f(h1)),
                     f2bf(v.z - bf2f(h2)), f2bf(v.w - bf2f(h3))};
        reinterpret_cast<bf16x4*>(XH)[i] = hi;
        reinterpret_cast<bf16x4*>(XL)[i] = lo;
    }
}

// ---------------------------------------------------------------------------
// Kernel 1: projection for ONE of q/k/v.  C[rows,1152] = X @ Wg + bg.
// 2-term split-bf16 (Ahi*B + Alo*B); full-wave global_load_lds staging only.
// XH/XL indexed by LOCAL row (m0); output row = m_base + local.
// which==2 (V): stored transposed [bh][d][s], chunk-swizzled (chunk ^= d&7).
// ---------------------------------------------------------------------------
__global__ __launch_bounds__(256)
void qkv_proj_one(const short* __restrict__ XH, const short* __restrict__ XL,
                  const short* __restrict__ WTn, const float* __restrict__ bias,
                  short* __restrict__ qkvW, int which, int m_base)
{
    __shared__ short aHi[128][32], aLo[128][32], bW[128][32];
    const int tid = threadIdx.x, lane = tid & 63, w = tid >> 6;
    const int c = lane & 15, g = lane >> 4;
    const int m0 = blockIdx.y * 128, n0 = blockIdx.x * 128;
    const int wm = (w >> 1) * 64, wn = (w & 1) * 64;
    const int lrow = lane >> 2, lch = (lane & 3) * 8;

    f32x4 acc[4][4] = {};

    for (int k0 = 0; k0 < E; k0 += 32) {
        __syncthreads();
        for (int t = 0; t < 2; ++t) {
            int row = w * 32 + t * 16;
            gload_lds16(XH + (long)(m0 + row + lrow) * E + k0 + lch, &aHi[row][0]);
            gload_lds16(XL + (long)(m0 + row + lrow) * E + k0 + lch, &aLo[row][0]);
            gload_lds16(WTn + (long)(n0 + row + lrow) * E + k0 + lch, &bW[row][0]);
        }
        __syncthreads();

        bf16x8 ah[4], al[4], bh[4];
        for (int i = 0; i < 4; ++i) {
            ah[i] = *reinterpret_cast<const bf16x8*>(&aHi[wm + i * 16 + c][g * 8]);
            al[i] = *reinterpret_cast<const bf16x8*>(&aLo[wm + i * 16 + c][g * 8]);
            bh[i] = *reinterpret_cast<const bf16x8*>(&bW[wn + i * 16 + c][g * 8]);
        }
        for (int i = 0; i < 4; ++i)
            for (int j = 0; j < 4; ++j) {
                acc[i][j] = MFMA16(ah[i], bh[j], acc[i][j]);
                acc[i][j] = MFMA16(al[i], bh[j], acc[i][j]);
            }
    }

    for (int j = 0; j < 4; ++j) {
        int n = n0 + wn + j * 16 + c;      // 0..1151
        float bv = bias[n];
        int hh = n / D, dd = n % D;
        if (which < 2) {
            for (int i = 0; i < 4; ++i) {
                int rowb = m_base + m0 + wm + i * 16 + g * 4;
                for (int r = 0; r < 4; ++r) {
                    int row = rowb + r;
                    int b = row >> 10, s = row & 1023;
                    qkvW[((long)(b * H + hh) * S + s) * D + dd] = f2bf(acc[i][j][r] + bv);
                }
            }
        } else {
            int cx = dd & 7;
            for (int i = 0; i < 4; ++i) {
                int srow = m_base + m0 + wm + i * 16 + g * 4;   // 4 consecutive s
                int b = srow >> 10, s = srow & 1023;
                int sw = (s & ~63) | ((((s >> 3) & 7) ^ cx) << 3) | (s & 7);
                bf16x4 pk = {f2bf(acc[i][j][0] + bv), f2bf(acc[i][j][1] + bv),
                             f2bf(acc[i][j][2] + bv), f2bf(acc[i][j][3] + bv)};
                *reinterpret_cast<bf16x4*>(&qkvW[((long)(b * H + hh) * D + dd) * S + sw]) = pk;
            }
        }
    }
}

// ---------------------------------------------------------------------------
// Kernel 2: flash attention.  Combined smem with explicit zero guard after K.
//   K [64][72] @0 | guard 24 @4608 | V [80][64] @4632 | P [4][32][72] @9752
// Full-wave gload staging (9 wave-rounds of 64 chunks per tensor).
// ---------------------------------------------------------------------------
__global__ __launch_bounds__(256)
void attn_fwd(const short* __restrict__ qkv, short* __restrict__ attn)
{
    __shared__ short smem[18968];
    const int tid = threadIdx.x, lane = tid & 63, w = tid >> 6;
    const int c = lane & 15, g = lane >> 4;
    const int q0 = blockIdx.x * 128;
    const int bh = blockIdx.y;
    const int b = bh >> 4, h = bh & 15;

    const short* Qb = qkv + (long)bh * (S * D);
    const short* Kb = qkv + QKV_T + (long)bh * (S * D);
    const short* Vt = qkv + 2 * QKV_T + (long)bh * ((long)D * S);

    // zero: K guard (24) + V d-pad rows 72..79 (512)
    if (tid < 24) smem[4608 + tid] = 0;
    for (int i = tid; i < 512; i += 256) smem[4632 + 4608 + i] = 0;

    bf16x8 qf[2][3];
    const bf16x8 zf = {};
    for (int i = 0; i < 2; ++i) {
        const short* qr = Qb + (long)(q0 + w * 32 + i * 16 + c) * D;
        qf[i][0] = *reinterpret_cast<const bf16x8*>(qr + g * 8);
        qf[i][1] = *reinterpret_cast<const bf16x8*>(qr + 32 + g * 8);
        qf[i][2] = (g == 0) ? *reinterpret_cast<const bf16x8*>(qr + 64) : zf;
    }

    const float scale = 0.11785113019775793f;  // 72^-0.5
    float m_run[2][4], l_run[2][4];
    f32x4 accO[2][5] = {};
    for (int i = 0; i < 2; ++i)
        for (int r = 0; r < 4; ++r) { m_run[i][r] = -1e30f; l_run[i][r] = 0.f; }

    for (int kt = 0; kt < 16; ++kt) {
        __syncthreads();
        const short* Ks = Kb + kt * 64 * D;
        const short* Vs = Vt + kt * 64;
        // 576 chunks each, full-wave rounds (wave w does rounds w, w+4, w+8)
        for (int r3 = w; r3 < 9; r3 += 4) {
            int id = r3 * 64 + lane;
            gload_lds16(Ks + (id / 9) * D + (id % 9) * 8, &smem[r3 * 512]);
            gload_lds16(Vs + (long)(id >> 3) * S + (id & 7) * 8, &smem[4632 + r3 * 512]);
        }
        __syncthreads();

        // S = Q K^T  (d-tail: A-frag zero for g>0; B reads land in-bounds,
        // row 63 tail reads hit the zero guard)
        f32x4 sAcc[2][4] = {};
        for (int dc = 0; dc < 3; ++dc) {
            bf16x8 bfr[4];
            for (int j = 0; j < 4; ++j)
                bfr[j] = *reinterpret_cast<const bf16x8*>(
                    &smem[(j * 16 + c) * 72 + dc * 32 + g * 8]);
            for (int i = 0; i < 2; ++i)
                for (int j = 0; j < 4; ++j)
                    sAcc[i][j] = MFMA16(qf[i][dc], bfr[j], sAcc[i][j]);
        }

        // online softmax (acc layout: row = g*4+r, col = c)
        for (int i = 0; i < 2; ++i) {
            for (int r = 0; r < 4; ++r) {
                float sv[4];
                float mx = -1e30f;
                for (int j = 0; j < 4; ++j) { sv[j] = sAcc[i][j][r] * scale; mx = fmaxf(mx, sv[j]); }
                mx = fmaxf(mx, __shfl_xor(mx, 1));
                mx = fmaxf(mx, __shfl_xor(mx, 2));
                mx = fmaxf(mx, __shfl_xor(mx, 4));
                mx = fmaxf(mx, __shfl_xor(mx, 8));
                float m_new = fmaxf(m_run[i][r], mx);
                float corr = __expf(m_run[i][r] - m_new);
                m_run[i][r] = m_new;
                float ps = 0.f;
                int prow = i * 16 + g * 4 + r;
                for (int j = 0; j < 4; ++j) {
                    float p = __expf(sv[j] - m_new);
                    ps += p;
                    smem[9752 + w * 2304 + prow * 72 + j * 16 + c] = f2bf(p);
                }
                ps += __shfl_xor(ps, 1);
                ps += __shfl_xor(ps, 2);
                ps += __shfl_xor(ps, 4);
                ps += __shfl_xor(ps, 8);
                l_run[i][r] = l_run[i][r] * corr + ps;
                for (int n = 0; n < 5; ++n) accO[i][n][r] *= corr;
            }
        }

        // O += P V  (V read with storage swizzle: chunk ^= c&7)
        for (int ks = 0; ks < 2; ++ks) {
            bf16x8 pa[2];
            for (int i = 0; i < 2; ++i)
                pa[i] = *reinterpret_cast<const bf16x8*>(
                    &smem[9752 + w * 2304 + (i * 16 + c) * 72 + ks * 32 + g * 8]);
            for (int n = 0; n < 5; ++n) {
                bf16x8 vb = *reinterpret_cast<const bf16x8*>(
                    &smem[4632 + (n * 16 + c) * 64 + ((ks * 4 + g) ^ (c & 7)) * 8]);
                for (int i = 0; i < 2; ++i)
                    accO[i][n] = MFMA16(pa[i], vb, accO[i][n]);
            }
        }
    }

    for (int i = 0; i < 2; ++i) {
        for (int n = 0; n < 5; ++n) {
            int dd = n * 16 + c;
            if (dd >= D) continue;
            for (int r = 0; r < 4; ++r) {
                int row = q0 + w * 32 + i * 16 + g * 4 + r;
                float val = accO[i][n][r] / l_run[i][r];
                attn[((long)(b * S + row)) * E + h * D + dd] = f2bf(val);
            }
        }
    }
}

// ---------------------------------------------------------------------------
// Kernel 3: out projection.  out[8192,1152] = attn(bf16) @ WTo(bf16) + b.
// ---------------------------------------------------------------------------
__global__ __launch_bounds__(256)
void out_proj(const short* __restrict__ Aat, const short* __restrict__ WTo,
              const float* __restrict__ bias, float* __restrict__ out)
{
    __shared__ short aT[128][32], bT[128][32];
    const int tid = threadIdx.x, lane = tid & 63, w = tid >> 6;
    const int c = lane & 15, g = lane >> 4;
    const int m0 = blockIdx.y * 128, n0 = blockIdx.x * 128;
    const int wm = (w >> 1) * 64, wn = (w & 1) * 64;
    const int lrow = lane >> 2, lch = (lane & 3) * 8;

    f32x4 acc[4][4] = {};
    for (int k0 = 0; k0 < E; k0 += 32) {
        __syncthreads();
        for (int t = 0; t < 2; ++t) {
            int row = w * 32 + t * 16;
            gload_lds16(Aat + (long)(m0 + row + lrow) * E + k0 + lch, &aT[row][0]);
            gload_lds16(WTo + (long)(n0 + row + lrow) * E + k0 + lch, &bT[row][0]);
        }
        __syncthreads();

        bf16x8 af[4], bf[4];
        for (int i = 0; i < 4; ++i) {
            af[i] = *reinterpret_cast<const bf16x8*>(&aT[wm + i * 16 + c][g * 8]);
            bf[i] = *reinterpret_cast<const bf16x8*>(&bT[wn + i * 16 + c][g * 8]);
        }
        for (int i = 0; i < 4; ++i)
            for (int j = 0; j < 4; ++j)
                acc[i][j] = MFMA16(af[i], bf[j], acc[i][j]);
    }

    for (int j = 0; j < 4; ++j) {
        int n = n0 + wn + j * 16 + c;
        float bv = bias[n];
        for (int i = 0; i < 4; ++i)
            for (int r = 0; r < 4; ++r) {
                int row = m0 + wm + i * 16 + g * 4 + r;
                out[(long)row * E + n] = acc[i][j][r] + bv;
            }
    }
}

// ---------------------------------------------------------------------------
// Workspace (shorts), peak 83.46 MB (< round-3-proven 86.1 MB):
//   Q[QKV_T] | K[QKV_T] | V^T[QKV_T] | A[QKV_T] | WT[3456*1152]
// Slot reuse: presplit hi/lo buffers live in whichever qkv/A slots are free;
// Q is projected in two M-halves so its hi/lo fits the A slot; WTo aliases WT.
// ---------------------------------------------------------------------------
extern "C" void kernel_launch(void* const* d_in, const int* in_sizes, int n_in,
                              void* d_out, int out_size, void* d_ws, size_t ws_size,
                              hipStream_t stream)
{
    const float* qin   = (const float*)d_in[0];
    const float* kin   = (const float*)d_in[1];
    const float* vin   = (const float*)d_in[2];
    const float* w_in  = (const float*)d_in[3];
    const float* b_in  = (const float*)d_in[4];
    const float* w_out = (const float*)d_in[5];
    const float* b_out = (const float*)d_in[6];

    short* ws  = (short*)d_ws;
    short* Q   = ws;
    short* K   = ws + QKV_T;
    short* V   = ws + 2 * QKV_T;
    short* A   = ws + 3 * QKV_T;
    short* WT  = ws + 4 * QKV_T;   // 3,981,312 shorts; WTo aliases this later
    short* WTo = WT;
    float* out = (float*)d_out;
    const long HALF = QKV_T / 2;

    wt_conv<<<dim3(108, 36), 256, 0, stream>>>(w_in, WT, E, N3);

    // V (which=2): hi/lo in Q,K slots (free)
    presplit<<<2048, 256, 0, stream>>>(vin, Q, K, QKV_T / 4);
    qkv_proj_one<<<dim3(9, 64), 256, 0, stream>>>(Q, K, WT + 2L * E * E, b_in + 2 * E, V, 2, 0);
    // K (which=1): hi in Q slot, lo in A slot
    presplit<<<2048, 256, 0, stream>>>(kin, Q, A, QKV_T / 4);
    qkv_proj_one<<<dim3(9, 64), 256, 0, stream>>>(Q, A, WT + 1L * E * E, b_in + E, K, 1, 0);
    // Q (which=0): two M-halves, hi/lo both in A slot
    presplit<<<2048, 256, 0, stream>>>(qin, A, A + HALF, HALF / 4);
    qkv_proj_one<<<dim3(9, 32), 256, 0, stream>>>(A, A + HALF, WT, b_in, Q, 0, 0);
    presplit<<<2048, 256, 0, stream>>>(qin + HALF, A, A + HALF, HALF / 4);
    qkv_proj_one<<<dim3(9, 32), 256, 0, stream>>>(A, A + HALF, WT, b_in, Q, 0, 4096);

    attn_fwd<<<dim3(8, 128), 256, 0, stream>>>(ws, A);
    wt_conv<<<dim3(36, 36), 256, 0, stream>>>(w_out, WTo, E, E);
    out_proj<<<dim3(9, 64), 256, 0, stream>>>(A, WTo, b_out, out);
}